// Round 3
// baseline (1780.621 us; speedup 1.0000x reference)
//
#include <hip/hip_runtime.h>
#include <hip/hip_bf16.h>

// Model: BiGRU encoder (B=128, S=512, E=32, Hh=64) + gated enc_outs +
// 15-step attention GRU decoder (H=128) + logits GEMM (1920x32000x128).
// R2 fix: ALL float tensors are fp32 (per reference dtypes); d_out is fp32.
// bf16 used only for internal staging (enc_outs, h_all, Wout copy) feeding
// the MFMA logits GEMM; fp32 accumulate throughout.

typedef unsigned short u16;
typedef unsigned int u32;
typedef __attribute__((ext_vector_type(8))) short short8;
typedef __attribute__((ext_vector_type(4))) float f32x4;

#define V_ 32000
#define E_ 32
#define H_ 128
#define B_ 128
#define S_ 512
#define TDEC 15   // T-1

__device__ __forceinline__ float bfu(u32 u) {
    union { u32 i; float f; } v; v.i = u << 16; return v.f;
}
__device__ __forceinline__ u16 f2bf(float f) {
    union { float f; u32 i; } v; v.f = f;
    u32 x = v.i;
    u32 r = (x + 0x7fffu + ((x >> 16) & 1u)) >> 16;
    return (u16)r;
}
__device__ __forceinline__ void bf8_to_f(const uint4 p, float* f) {
    f[0] = bfu(p.x & 0xffffu); f[1] = bfu(p.x >> 16);
    f[2] = bfu(p.y & 0xffffu); f[3] = bfu(p.y >> 16);
    f[4] = bfu(p.z & 0xffffu); f[5] = bfu(p.z >> 16);
    f[6] = bfu(p.w & 0xffffu); f[7] = bfu(p.w >> 16);
}
__device__ __forceinline__ float sigm(float x) { return 1.f / (1.f + expf(-x)); }

// ---------------------------------------------------------------------------
// K1: encoder BiGRU. grid = 256 (b in [0,128), dir in {0,1}), block = 192.
// Thread j owns gate row j; W rows in registers (fp32). h in LDS. 512 steps.
// outputs: fp32 [B][S][H] (front of d_out).
// ---------------------------------------------------------------------------
__global__ __launch_bounds__(192) void encoder_kernel(
    const int* __restrict__ inputs, const float* __restrict__ emb,
    const float* __restrict__ Wih_f, const float* __restrict__ Whh_f,
    const float* __restrict__ bih_f, const float* __restrict__ bhh_f,
    const float* __restrict__ Wih_b, const float* __restrict__ Whh_b,
    const float* __restrict__ bih_b, const float* __restrict__ bhh_b,
    float* __restrict__ outputs, float* __restrict__ sn)
{
    const int j = threadIdx.x;              // 0..191
    const int b = blockIdx.x & 127;
    const int dir = blockIdx.x >> 7;

    const float* Wih = dir ? Wih_b : Wih_f;
    const float* Whh = dir ? Whh_b : Whh_f;
    const float bi = (dir ? bih_b : bih_f)[j];
    const float bh = (dir ? bhh_b : bhh_f)[j];

    float wih[E_];
    #pragma unroll
    for (int k = 0; k < E_; k++) wih[k] = Wih[j * E_ + k];
    float whh[64];
    #pragma unroll
    for (int k = 0; k < 64; k++) whh[k] = Whh[j * 64 + k];

    __shared__ float hs[64];
    __shared__ float xe[E_];
    __shared__ float sgi[192];
    __shared__ float sgh[192];
    if (j < 64) hs[j] = 0.f;

    const int* inrow = inputs + b * S_;

    for (int s = 0; s < S_; s++) {
        const int ts = dir ? (S_ - 1 - s) : s;
        __syncthreads();                     // hs from prev iter visible
        if (j < E_) {
            const unsigned idx = (unsigned)inrow[ts];
            xe[j] = emb[idx * E_ + j];
        }
        __syncthreads();

        float g0 = 0.f, g1 = 0.f, g2 = 0.f, g3 = 0.f;
        #pragma unroll
        for (int k = 0; k < E_; k += 4) {
            g0 += xe[k]     * wih[k];
            g1 += xe[k + 1] * wih[k + 1];
            g2 += xe[k + 2] * wih[k + 2];
            g3 += xe[k + 3] * wih[k + 3];
        }
        const float gi = bi + ((g0 + g1) + (g2 + g3));

        float h0 = 0.f, h1 = 0.f, h2 = 0.f, h3 = 0.f;
        #pragma unroll
        for (int k = 0; k < 64; k += 4) {
            h0 += hs[k]     * whh[k];
            h1 += hs[k + 1] * whh[k + 1];
            h2 += hs[k + 2] * whh[k + 2];
            h3 += hs[k + 3] * whh[k + 3];
        }
        const float gh = bh + ((h0 + h1) + (h2 + h3));

        sgi[j] = gi; sgh[j] = gh;
        __syncthreads();

        if (j < 64) {
            const float r = sigm(sgi[j] + sgh[j]);
            const float z = sigm(sgi[64 + j] + sgh[64 + j]);
            const float n = tanhf(sgi[128 + j] + r * sgh[128 + j]);
            const float hn = (1.f - z) * n + z * hs[j];
            hs[j] = hn;
            outputs[((b << 9) + ts) * H_ + (dir << 6) + j] = hn;
            if (s == S_ - 1) sn[(b << 7) + (dir << 6) + j] = hn;
        }
    }
}

// ---------------------------------------------------------------------------
// K2: t2[b][h] = sn[b] . W2[h] + b2[h].  grid=128, block=128. All fp32.
// ---------------------------------------------------------------------------
__global__ __launch_bounds__(128) void t2_kernel(
    const float* __restrict__ sn, const float* __restrict__ W2,
    const float* __restrict__ b2, float* __restrict__ t2)
{
    const int b = blockIdx.x, h = threadIdx.x;
    __shared__ float s_[H_];
    s_[h] = sn[b * H_ + h];
    __syncthreads();
    const float4* wr = (const float4*)(W2 + h * H_);
    float a0 = 0.f, a1 = 0.f, a2 = 0.f, a3 = 0.f;
    #pragma unroll 4
    for (int k = 0; k < H_ / 4; k++) {
        const float4 p = wr[k];
        a0 += s_[4 * k + 0] * p.x; a1 += s_[4 * k + 1] * p.y;
        a2 += s_[4 * k + 2] * p.z; a3 += s_[4 * k + 3] * p.w;
    }
    t2[b * H_ + h] = ((a0 + a1) + (a2 + a3)) + b2[h];
}

// ---------------------------------------------------------------------------
// K3: enc[b][s][h] = outputs[b][s][h] * sigmoid(outputs[b][s].W1[h]+b1[h]+t2[b][h])
// grid = 65536 (b*512+s), block = 128. outputs fp32 -> enc bf16.
// ---------------------------------------------------------------------------
__global__ __launch_bounds__(128) void gate_kernel(
    const float* __restrict__ outputs, const float* __restrict__ W1,
    const float* __restrict__ b1, const float* __restrict__ t2,
    u16* __restrict__ enc)
{
    const int bs = blockIdx.x;
    const int b = bs >> 9;
    const int h = threadIdx.x;
    __shared__ float so[H_];
    so[h] = outputs[bs * H_ + h];
    __syncthreads();
    const float4* wr = (const float4*)(W1 + h * H_);
    float a0 = 0.f, a1 = 0.f, a2 = 0.f, a3 = 0.f;
    #pragma unroll 4
    for (int k = 0; k < H_ / 4; k++) {
        const float4 p = wr[k];
        a0 += so[4 * k + 0] * p.x; a1 += so[4 * k + 1] * p.y;
        a2 += so[4 * k + 2] * p.z; a3 += so[4 * k + 3] * p.w;
    }
    const float pre = ((a0 + a1) + (a2 + a3)) + b1[h] + t2[b * H_ + h];
    enc[bs * H_ + h] = f2bf(so[h] * sigm(pre));
}

// ---------------------------------------------------------------------------
// K4: W_out fp32 -> bf16 copy (for MFMA). 4 elems/thread.
// grid = V_*H_/1024 = 4000, block = 256.
// ---------------------------------------------------------------------------
__global__ __launch_bounds__(256) void wout_cvt_kernel(
    const float* __restrict__ Wout, u16* __restrict__ Woutb)
{
    const int i = (blockIdx.x * 256 + threadIdx.x) * 4;
    const float4 p = *(const float4*)(Wout + i);
    ushort4 q;
    q.x = f2bf(p.x); q.y = f2bf(p.y); q.z = f2bf(p.z); q.w = f2bf(p.w);
    *(ushort4*)(Woutb + i) = q;
}

// ---------------------------------------------------------------------------
// K5: decoder. grid = 128 (one WG per batch), block = 256. 15 steps:
// attention (softmax over S=512, enc bf16) + GRU (fp32 weights).
// ---------------------------------------------------------------------------
__global__ __launch_bounds__(256) void decoder_kernel(
    const int* __restrict__ targets, const float* __restrict__ emb,
    const float* __restrict__ Wihd, const float* __restrict__ Whhd,
    const float* __restrict__ bihd, const float* __restrict__ bhhd,
    const u16* __restrict__ enc, const float* __restrict__ sn,
    u16* __restrict__ h_all)
{
    const int b = blockIdx.x;
    const int tid = threadIdx.x;
    __shared__ float h[H_];
    __shared__ float sc[S_];
    __shared__ float xv[H_ + E_];     // [c(128), e(32)]
    __shared__ float red[256];
    __shared__ float chalf[2][H_];
    __shared__ float sgi[3 * H_];
    __shared__ float sgh[3 * H_];

    if (tid < H_) h[tid] = sn[b * H_ + tid];
    __syncthreads();

    const u16* encb = enc + b * S_ * H_;

    for (int t = 0; t < TDEC; t++) {
        const int word = targets[b * 16 + t];

        // ---- pass 1: scores sc[s] = h . enc[b][s] ----
        for (int s = tid; s < S_; s += 256) {
            const u16* row = encb + s * H_;
            float a0 = 0.f, a1 = 0.f, a2 = 0.f, a3 = 0.f;
            for (int k = 0; k < H_; k += 8) {
                uint4 p = *(const uint4*)(row + k);
                float f[8]; bf8_to_f(p, f);
                a0 += h[k + 0] * f[0]; a1 += h[k + 1] * f[1];
                a2 += h[k + 2] * f[2]; a3 += h[k + 3] * f[3];
                a0 += h[k + 4] * f[4]; a1 += h[k + 5] * f[5];
                a2 += h[k + 6] * f[6]; a3 += h[k + 7] * f[7];
            }
            sc[s] = (a0 + a1) + (a2 + a3);
        }
        __syncthreads();

        // ---- softmax over 512 ----
        red[tid] = fmaxf(sc[tid], sc[tid + 256]);
        __syncthreads();
        for (int off = 128; off > 0; off >>= 1) {
            if (tid < off) red[tid] = fmaxf(red[tid], red[tid + off]);
            __syncthreads();
        }
        const float m = red[0];
        __syncthreads();
        const float e0 = expf(sc[tid] - m);
        const float e1 = expf(sc[tid + 256] - m);
        red[tid] = e0 + e1;
        __syncthreads();
        for (int off = 128; off > 0; off >>= 1) {
            if (tid < off) red[tid] = red[tid] + red[tid + off];
            __syncthreads();
        }
        const float inv = 1.f / red[0];
        __syncthreads();
        sc[tid] = e0 * inv;
        sc[tid + 256] = e1 * inv;
        __syncthreads();

        // ---- pass 2: c[k] = sum_s alpha[s] * enc[b][s][k] ----
        {
            const int k = tid & 127;
            const int half = tid >> 7;
            const u16* basep = encb + (half * 256) * H_ + k;
            const float* al = sc + half * 256;
            float c0 = 0.f, c1 = 0.f, c2 = 0.f, c3 = 0.f;
            for (int s = 0; s < 256; s += 4) {
                c0 += al[s + 0] * bfu(basep[(s + 0) * H_]);
                c1 += al[s + 1] * bfu(basep[(s + 1) * H_]);
                c2 += al[s + 2] * bfu(basep[(s + 2) * H_]);
                c3 += al[s + 3] * bfu(basep[(s + 3) * H_]);
            }
            chalf[half][k] = (c0 + c1) + (c2 + c3);
        }
        __syncthreads();
        if (tid < H_) xv[tid] = chalf[0][tid] + chalf[1][tid];
        else if (tid < H_ + E_) xv[tid] = emb[(unsigned)word * E_ + (tid - H_)];
        __syncthreads();

        // ---- gates: gi = x.Wihd[j]+bihd[j], gh = h.Whhd[j]+bhhd[j], j<384 ----
        for (int j = tid; j < 3 * H_; j += 256) {
            const float4* wr = (const float4*)(Wihd + j * (H_ + E_));
            float a0 = 0.f, a1 = 0.f, a2 = 0.f, a3 = 0.f;
            for (int k = 0; k < (H_ + E_) / 4; k++) {
                const float4 p = wr[k];
                a0 += xv[4 * k + 0] * p.x; a1 += xv[4 * k + 1] * p.y;
                a2 += xv[4 * k + 2] * p.z; a3 += xv[4 * k + 3] * p.w;
            }
            sgi[j] = ((a0 + a1) + (a2 + a3)) + bihd[j];

            const float4* hr = (const float4*)(Whhd + j * H_);
            float b0 = 0.f, b1_ = 0.f, b2_ = 0.f, b3 = 0.f;
            for (int k = 0; k < H_ / 4; k++) {
                const float4 p = hr[k];
                b0  += h[4 * k + 0] * p.x; b1_ += h[4 * k + 1] * p.y;
                b2_ += h[4 * k + 2] * p.z; b3  += h[4 * k + 3] * p.w;
            }
            sgh[j] = ((b0 + b1_) + (b2_ + b3)) + bhhd[j];
        }
        __syncthreads();

        if (tid < H_) {
            const float r = sigm(sgi[tid] + sgh[tid]);
            const float z = sigm(sgi[H_ + tid] + sgh[H_ + tid]);
            const float n = tanhf(sgi[2 * H_ + tid] + r * sgh[2 * H_ + tid]);
            const float hn = (1.f - z) * n + z * h[tid];
            h[tid] = hn;
            h_all[(t * B_ + b) * H_ + tid] = f2bf(hn);
        }
        __syncthreads();
    }
}

// ---------------------------------------------------------------------------
// K6: logits = h_all @ Woutb^T + b_out. MFMA bf16 NT GEMM, fp32 out.
// M=1920 (t*128+b), N=32000, K=128. WG = 4 waves, tile 64(M)x64(N);
// wave w owns m-subtile w (16 rows) x 64 cols. grid = (500, 30).
// Output: out[(b*15 + t)*32000 + n], fp32.
// ---------------------------------------------------------------------------
__global__ __launch_bounds__(256) void logits_kernel(
    const u16* __restrict__ hall, const u16* __restrict__ Woutb,
    const float* __restrict__ bout, float* __restrict__ out)
{
    const int l = threadIdx.x & 63;
    const int w = threadIdx.x >> 6;
    const int tile_n = blockIdx.x * 64;
    const int tile_m = blockIdx.y * 64 + w * 16;

    f32x4 acc[4] = {};
    const int row_a = tile_m + (l & 15);
    const int kb = (l >> 4) * 8;

    #pragma unroll
    for (int kk = 0; kk < 4; kk++) {
        const int k0 = kk * 32 + kb;
        const short8 af = *(const short8*)(hall + row_a * H_ + k0);
        #pragma unroll
        for (int i = 0; i < 4; i++) {
            const int n = tile_n + i * 16 + (l & 15);
            const short8 bv = *(const short8*)(Woutb + n * H_ + k0);
            acc[i] = __builtin_amdgcn_mfma_f32_16x16x32_bf16(af, bv, acc[i], 0, 0, 0);
        }
    }

    const int m_base = tile_m + (l >> 4) * 4;
    #pragma unroll
    for (int i = 0; i < 4; i++) {
        const int n = tile_n + i * 16 + (l & 15);
        const float bias = bout[n];
        #pragma unroll
        for (int r = 0; r < 4; r++) {
            const int m = m_base + r;
            const int t = m >> 7;
            const int bb = m & 127;
            out[(size_t)(bb * TDEC + t) * V_ + n] = acc[i][r] + bias;
        }
    }
}

// ---------------------------------------------------------------------------
extern "C" void kernel_launch(void* const* d_in, const int* in_sizes, int n_in,
                              void* d_out, int out_size, void* d_ws, size_t ws_size,
                              hipStream_t stream) {
    const int*   inputs  = (const int*)d_in[0];
    const int*   targets = (const int*)d_in[1];
    const float* emb     = (const float*)d_in[2];
    const float* Wih_f   = (const float*)d_in[3];
    const float* Whh_f   = (const float*)d_in[4];
    const float* bih_f   = (const float*)d_in[5];
    const float* bhh_f   = (const float*)d_in[6];
    const float* Wih_b   = (const float*)d_in[7];
    const float* Whh_b   = (const float*)d_in[8];
    const float* bih_b   = (const float*)d_in[9];
    const float* bhh_b   = (const float*)d_in[10];
    const float* W1      = (const float*)d_in[11];
    const float* b1      = (const float*)d_in[12];
    const float* W2      = (const float*)d_in[13];
    const float* b2      = (const float*)d_in[14];
    const float* Wihd    = (const float*)d_in[15];
    const float* Whhd    = (const float*)d_in[16];
    const float* bihd    = (const float*)d_in[17];
    const float* bhhd    = (const float*)d_in[18];
    const float* Wout    = (const float*)d_in[19];
    const float* bout    = (const float*)d_in[20];
    float* out = (float*)d_out;

    // Staging at the front of d_out (245.76 MB total). Logits kernel runs
    // last and overwrites every element of d_out with the real output.
    float* outputs = out;                              // fp32 B*S*H = 33,554,432 B
    u16*   enc     = (u16*)((char*)d_out + 33554432);  // bf16 B*S*H = 16,777,216 B

    // d_ws: small state only (8.82 MB total).
    char* ws = (char*)d_ws;
    float* sn    = (float*)(ws);                 // B*H  f32    =  65,536 B
    float* t2    = (float*)(ws + 65536);         // B*H  f32    =  65,536 B
    u16*   h_all = (u16*)(ws + 131072);          // 15*B*H bf16 = 491,520 B
    u16*   Woutb = (u16*)(ws + 622592);          // V*H bf16    = 8,192,000 B

    encoder_kernel<<<256, 192, 0, stream>>>(inputs, emb, Wih_f, Whh_f, bih_f, bhh_f,
                                            Wih_b, Whh_b, bih_b, bhh_b, outputs, sn);
    t2_kernel<<<128, 128, 0, stream>>>(sn, W2, b2, t2);
    gate_kernel<<<65536, 128, 0, stream>>>(outputs, W1, b1, t2, enc);
    wout_cvt_kernel<<<V_ * H_ / 1024, 256, 0, stream>>>(Wout, Woutb);
    decoder_kernel<<<128, 256, 0, stream>>>(targets, emb, Wihd, Whhd, bihd, bhhd,
                                            enc, sn, h_all);
    logits_kernel<<<dim3(500, 30), 256, 0, stream>>>(h_all, Woutb, bout, out);
}

// Round 4
// 1488.386 us; speedup vs baseline: 1.1963x; 1.1963x over previous
//
#include <hip/hip_runtime.h>
#include <hip/hip_bf16.h>

// Model: BiGRU encoder (B=128, S=512, E=32, Hh=64) + gated enc_outs +
// 15-step attention GRU decoder (H=128) + logits GEMM (1920x32000x128).
// fp32 inputs/outputs; bf16 internal staging (outputs, enc, h_all, W1b, Woutb).
//
// R4: (a) encoder rewritten wave-synchronous: 1 (b,dir) chain per 64-lane wave,
//     all gate weights in VGPRs, 1 barrier/step, fast exp activations.
//     (b) gate rewritten as bf16 MFMA GEMM (65536x128x128) over bf16 outputs.

typedef unsigned short u16;
typedef unsigned int u32;
typedef __attribute__((ext_vector_type(8))) short short8;
typedef __attribute__((ext_vector_type(4))) float f32x4;

#define V_ 32000
#define E_ 32
#define H_ 128
#define B_ 128
#define S_ 512
#define TDEC 15   // T-1

__device__ __forceinline__ float bfu(u32 u) {
    union { u32 i; float f; } v; v.i = u << 16; return v.f;
}
__device__ __forceinline__ u16 f2bf(float f) {
    union { float f; u32 i; } v; v.f = f;
    u32 x = v.i;
    u32 r = (x + 0x7fffu + ((x >> 16) & 1u)) >> 16;
    return (u16)r;
}
__device__ __forceinline__ void bf8_to_f(const uint4 p, float* f) {
    f[0] = bfu(p.x & 0xffffu); f[1] = bfu(p.x >> 16);
    f[2] = bfu(p.y & 0xffffu); f[3] = bfu(p.y >> 16);
    f[4] = bfu(p.z & 0xffffu); f[5] = bfu(p.z >> 16);
    f[6] = bfu(p.w & 0xffffu); f[7] = bfu(p.w >> 16);
}
__device__ __forceinline__ float sigm(float x) { return 1.f / (1.f + expf(-x)); }
__device__ __forceinline__ float sigm_fast(float x) { return 1.f / (1.f + __expf(-x)); }
__device__ __forceinline__ float tanh_fast(float x) {
    const float t = __expf(2.f * x);          // args bounded ~|x|<12 here: no overflow
    return (t - 1.f) / (t + 1.f);
}

// ---------------------------------------------------------------------------
// K1: encoder BiGRU, wave-synchronous. grid = 256 (b, dir), block = 64 = 1 wave.
// Lane j owns gate rows j, 64+j, 128+j (all weights in VGPRs ~288 regs) and
// state element h[j]. h/xe broadcast via LDS; ONE __syncthreads per step.
// outputs: bf16 [B][S][H]; sn: fp32 [B][H].
// ---------------------------------------------------------------------------
__global__ __launch_bounds__(64, 1) void encoder_kernel(
    const int* __restrict__ inputs, const float* __restrict__ emb,
    const float* __restrict__ Wih_f, const float* __restrict__ Whh_f,
    const float* __restrict__ bih_f, const float* __restrict__ bhh_f,
    const float* __restrict__ Wih_b, const float* __restrict__ Whh_b,
    const float* __restrict__ bih_b, const float* __restrict__ bhh_b,
    u16* __restrict__ outputs, float* __restrict__ sn)
{
    const int j = threadIdx.x;              // 0..63
    const int b = blockIdx.x & 127;
    const int dir = blockIdx.x >> 7;

    const float* Wih = dir ? Wih_b : Wih_f;
    const float* Whh = dir ? Whh_b : Whh_f;
    const float* bih = dir ? bih_b : bih_f;
    const float* bhh = dir ? bhh_b : bhh_f;

    const float bi0 = bih[j], bi1 = bih[64 + j], bi2 = bih[128 + j];
    const float bh0 = bhh[j], bh1 = bhh[64 + j], bh2 = bhh[128 + j];

    float wi0[E_], wi1[E_], wi2[E_];
    #pragma unroll
    for (int k = 0; k < E_; k += 4) {
        *(float4*)(wi0 + k) = *(const float4*)(Wih + j * E_ + k);
        *(float4*)(wi1 + k) = *(const float4*)(Wih + (64 + j) * E_ + k);
        *(float4*)(wi2 + k) = *(const float4*)(Wih + (128 + j) * E_ + k);
    }
    float wh0[64], wh1[64], wh2[64];
    #pragma unroll
    for (int k = 0; k < 64; k += 4) {
        *(float4*)(wh0 + k) = *(const float4*)(Whh + j * 64 + k);
        *(float4*)(wh1 + k) = *(const float4*)(Whh + (64 + j) * 64 + k);
        *(float4*)(wh2 + k) = *(const float4*)(Whh + (128 + j) * 64 + k);
    }

    __shared__ float hs[64];
    __shared__ float xe[E_];
    hs[j] = 0.f;
    float hmine = 0.f;

    const int* inrow = inputs + b * S_;

    // prefetch embedding row for step 0
    float xpre = 0.f;
    {
        const int ts0 = dir ? (S_ - 1) : 0;
        const unsigned idx = (unsigned)inrow[ts0];
        if (j < E_) xpre = emb[idx * E_ + j];
    }

    for (int s = 0; s < S_; s++) {
        const int cts = dir ? (S_ - 1 - s) : s;
        if (j < E_) xe[j] = xpre;
        __syncthreads();   // xe + hs (written at end of prev step) visible

        // prefetch next step's embedding row (latency hidden by the dots)
        if (s + 1 < S_) {
            const int nts = dir ? (S_ - 2 - s) : (s + 1);
            const unsigned idx = (unsigned)inrow[nts];
            if (j < E_) xpre = emb[idx * E_ + j];
        }

        float gi0 = bi0, gi1 = bi1, gi2 = bi2;
        #pragma unroll
        for (int k = 0; k < E_; k += 4) {
            const float4 x = *(const float4*)(xe + k);
            gi0 += x.x * wi0[k] + x.y * wi0[k + 1] + x.z * wi0[k + 2] + x.w * wi0[k + 3];
            gi1 += x.x * wi1[k] + x.y * wi1[k + 1] + x.z * wi1[k + 2] + x.w * wi1[k + 3];
            gi2 += x.x * wi2[k] + x.y * wi2[k + 1] + x.z * wi2[k + 2] + x.w * wi2[k + 3];
        }
        float gh0 = bh0, gh1 = bh1, gh2 = bh2;
        #pragma unroll
        for (int k = 0; k < 64; k += 4) {
            const float4 hv = *(const float4*)(hs + k);
            gh0 += hv.x * wh0[k] + hv.y * wh0[k + 1] + hv.z * wh0[k + 2] + hv.w * wh0[k + 3];
            gh1 += hv.x * wh1[k] + hv.y * wh1[k + 1] + hv.z * wh1[k + 2] + hv.w * wh1[k + 3];
            gh2 += hv.x * wh2[k] + hv.y * wh2[k + 1] + hv.z * wh2[k + 2] + hv.w * wh2[k + 3];
        }

        const float r = sigm_fast(gi0 + gh0);
        const float z = sigm_fast(gi1 + gh1);
        const float n = tanh_fast(gi2 + r * gh2);
        const float hn = (1.f - z) * n + z * hmine;
        hmine = hn;
        // single wave: all lanes' hs reads (above) retire before this write issues
        hs[j] = hn;
        outputs[((b << 9) + cts) * H_ + (dir << 6) + j] = f2bf(hn);
    }
    sn[(b << 7) + (dir << 6) + j] = hmine;
}

// ---------------------------------------------------------------------------
// K2: t2[b][h] = sn[b] . W2[h] + b2[h].  grid=128, block=128. All fp32.
// ---------------------------------------------------------------------------
__global__ __launch_bounds__(128) void t2_kernel(
    const float* __restrict__ sn, const float* __restrict__ W2,
    const float* __restrict__ b2, float* __restrict__ t2)
{
    const int b = blockIdx.x, h = threadIdx.x;
    __shared__ float s_[H_];
    s_[h] = sn[b * H_ + h];
    __syncthreads();
    const float4* wr = (const float4*)(W2 + h * H_);
    float a0 = 0.f, a1 = 0.f, a2 = 0.f, a3 = 0.f;
    #pragma unroll 4
    for (int k = 0; k < H_ / 4; k++) {
        const float4 p = wr[k];
        a0 += s_[4 * k + 0] * p.x; a1 += s_[4 * k + 1] * p.y;
        a2 += s_[4 * k + 2] * p.z; a3 += s_[4 * k + 3] * p.w;
    }
    t2[b * H_ + h] = ((a0 + a1) + (a2 + a3)) + b2[h];
}

// ---------------------------------------------------------------------------
// K3: fp32 -> bf16 conversion (used for W1 and W_out). 4 elems/thread.
// ---------------------------------------------------------------------------
__global__ __launch_bounds__(256) void cvt_bf16_kernel(
    const float* __restrict__ src, u16* __restrict__ dst)
{
    const int i = (blockIdx.x * 256 + threadIdx.x) * 4;
    const float4 p = *(const float4*)(src + i);
    ushort4 q;
    q.x = f2bf(p.x); q.y = f2bf(p.y); q.z = f2bf(p.z); q.w = f2bf(p.w);
    *(ushort4*)(dst + i) = q;
}

// ---------------------------------------------------------------------------
// K4: gate via MFMA. pre[m][n] = outputs[m] . W1[n];
// enc[m][n] = outputs[m][n] * sigmoid(pre + b1[n] + t2[b][n]),  b = m>>9.
// M=65536 rows, N=128, K=128. Block = 4 waves, tile 64(M)x128(N). grid=1024.
// ---------------------------------------------------------------------------
__global__ __launch_bounds__(256) void gate_mfma_kernel(
    const u16* __restrict__ outputs, const u16* __restrict__ W1b,
    const float* __restrict__ b1, const float* __restrict__ t2,
    u16* __restrict__ enc)
{
    const int l = threadIdx.x & 63;
    const int w = threadIdx.x >> 6;
    const int tile_m = blockIdx.x * 64 + w * 16;
    const int row_a = tile_m + (l & 15);
    const int kb = (l >> 4) * 8;
    const int b = blockIdx.x >> 3;           // 8 blocks of 64 rows per batch

    f32x4 acc[8] = {};
    #pragma unroll
    for (int kk = 0; kk < 4; kk++) {
        const int k0 = kk * 32 + kb;
        const short8 af = *(const short8*)(outputs + row_a * H_ + k0);
        #pragma unroll
        for (int i = 0; i < 8; i++) {
            const int n = i * 16 + (l & 15);
            const short8 bv = *(const short8*)(W1b + n * H_ + k0);
            acc[i] = __builtin_amdgcn_mfma_f32_16x16x32_bf16(af, bv, acc[i], 0, 0, 0);
        }
    }

    const int m_base = tile_m + (l >> 4) * 4;
    #pragma unroll
    for (int i = 0; i < 8; i++) {
        const int n = i * 16 + (l & 15);
        const float bias = b1[n] + t2[b * H_ + n];
        #pragma unroll
        for (int r = 0; r < 4; r++) {
            const int m = m_base + r;
            const float g = sigm_fast(acc[i][r] + bias);
            const float o = bfu(outputs[m * H_ + n]);
            enc[m * H_ + n] = f2bf(o * g);
        }
    }
}

// ---------------------------------------------------------------------------
// K5: decoder. grid = 128 (one WG per batch), block = 256. 15 steps:
// attention (softmax over S=512, enc bf16) + GRU (fp32 weights).
// ---------------------------------------------------------------------------
__global__ __launch_bounds__(256) void decoder_kernel(
    const int* __restrict__ targets, const float* __restrict__ emb,
    const float* __restrict__ Wihd, const float* __restrict__ Whhd,
    const float* __restrict__ bihd, const float* __restrict__ bhhd,
    const u16* __restrict__ enc, const float* __restrict__ sn,
    u16* __restrict__ h_all)
{
    const int b = blockIdx.x;
    const int tid = threadIdx.x;
    __shared__ float h[H_];
    __shared__ float sc[S_];
    __shared__ float xv[H_ + E_];     // [c(128), e(32)]
    __shared__ float red[256];
    __shared__ float chalf[2][H_];
    __shared__ float sgi[3 * H_];
    __shared__ float sgh[3 * H_];

    if (tid < H_) h[tid] = sn[b * H_ + tid];
    __syncthreads();

    const u16* encb = enc + b * S_ * H_;

    for (int t = 0; t < TDEC; t++) {
        const int word = targets[b * 16 + t];

        // ---- pass 1: scores sc[s] = h . enc[b][s] ----
        for (int s = tid; s < S_; s += 256) {
            const u16* row = encb + s * H_;
            float a0 = 0.f, a1 = 0.f, a2 = 0.f, a3 = 0.f;
            for (int k = 0; k < H_; k += 8) {
                uint4 p = *(const uint4*)(row + k);
                float f[8]; bf8_to_f(p, f);
                a0 += h[k + 0] * f[0]; a1 += h[k + 1] * f[1];
                a2 += h[k + 2] * f[2]; a3 += h[k + 3] * f[3];
                a0 += h[k + 4] * f[4]; a1 += h[k + 5] * f[5];
                a2 += h[k + 6] * f[6]; a3 += h[k + 7] * f[7];
            }
            sc[s] = (a0 + a1) + (a2 + a3);
        }
        __syncthreads();

        // ---- softmax over 512 ----
        red[tid] = fmaxf(sc[tid], sc[tid + 256]);
        __syncthreads();
        for (int off = 128; off > 0; off >>= 1) {
            if (tid < off) red[tid] = fmaxf(red[tid], red[tid + off]);
            __syncthreads();
        }
        const float m = red[0];
        __syncthreads();
        const float e0 = expf(sc[tid] - m);
        const float e1 = expf(sc[tid + 256] - m);
        red[tid] = e0 + e1;
        __syncthreads();
        for (int off = 128; off > 0; off >>= 1) {
            if (tid < off) red[tid] = red[tid] + red[tid + off];
            __syncthreads();
        }
        const float inv = 1.f / red[0];
        __syncthreads();
        sc[tid] = e0 * inv;
        sc[tid + 256] = e1 * inv;
        __syncthreads();

        // ---- pass 2: c[k] = sum_s alpha[s] * enc[b][s][k] ----
        {
            const int k = tid & 127;
            const int half = tid >> 7;
            const u16* basep = encb + (half * 256) * H_ + k;
            const float* al = sc + half * 256;
            float c0 = 0.f, c1 = 0.f, c2 = 0.f, c3 = 0.f;
            for (int s = 0; s < 256; s += 4) {
                c0 += al[s + 0] * bfu(basep[(s + 0) * H_]);
                c1 += al[s + 1] * bfu(basep[(s + 1) * H_]);
                c2 += al[s + 2] * bfu(basep[(s + 2) * H_]);
                c3 += al[s + 3] * bfu(basep[(s + 3) * H_]);
            }
            chalf[half][k] = (c0 + c1) + (c2 + c3);
        }
        __syncthreads();
        if (tid < H_) xv[tid] = chalf[0][tid] + chalf[1][tid];
        else if (tid < H_ + E_) xv[tid] = emb[(unsigned)word * E_ + (tid - H_)];
        __syncthreads();

        // ---- gates ----
        for (int j = tid; j < 3 * H_; j += 256) {
            const float4* wr = (const float4*)(Wihd + j * (H_ + E_));
            float a0 = 0.f, a1 = 0.f, a2 = 0.f, a3 = 0.f;
            for (int k = 0; k < (H_ + E_) / 4; k++) {
                const float4 p = wr[k];
                a0 += xv[4 * k + 0] * p.x; a1 += xv[4 * k + 1] * p.y;
                a2 += xv[4 * k + 2] * p.z; a3 += xv[4 * k + 3] * p.w;
            }
            sgi[j] = ((a0 + a1) + (a2 + a3)) + bihd[j];

            const float4* hr = (const float4*)(Whhd + j * H_);
            float b0 = 0.f, b1_ = 0.f, b2_ = 0.f, b3 = 0.f;
            for (int k = 0; k < H_ / 4; k++) {
                const float4 p = hr[k];
                b0  += h[4 * k + 0] * p.x; b1_ += h[4 * k + 1] * p.y;
                b2_ += h[4 * k + 2] * p.z; b3  += h[4 * k + 3] * p.w;
            }
            sgh[j] = ((b0 + b1_) + (b2_ + b3)) + bhhd[j];
        }
        __syncthreads();

        if (tid < H_) {
            const float r = sigm(sgi[tid] + sgh[tid]);
            const float z = sigm(sgi[H_ + tid] + sgh[H_ + tid]);
            const float n = tanhf(sgi[2 * H_ + tid] + r * sgh[2 * H_ + tid]);
            const float hn = (1.f - z) * n + z * h[tid];
            h[tid] = hn;
            h_all[(t * B_ + b) * H_ + tid] = f2bf(hn);
        }
        __syncthreads();
    }
}

// ---------------------------------------------------------------------------
// K6: logits = h_all @ Woutb^T + b_out. MFMA bf16 NT GEMM, fp32 out.
// M=1920 (t*128+b), N=32000, K=128. grid=(500,30), block=256.
// Output: out[(b*15 + t)*32000 + n], fp32.
// ---------------------------------------------------------------------------
__global__ __launch_bounds__(256) void logits_kernel(
    const u16* __restrict__ hall, const u16* __restrict__ Woutb,
    const float* __restrict__ bout, float* __restrict__ out)
{
    const int l = threadIdx.x & 63;
    const int w = threadIdx.x >> 6;
    const int tile_n = blockIdx.x * 64;
    const int tile_m = blockIdx.y * 64 + w * 16;

    f32x4 acc[4] = {};
    const int row_a = tile_m + (l & 15);
    const int kb = (l >> 4) * 8;

    #pragma unroll
    for (int kk = 0; kk < 4; kk++) {
        const int k0 = kk * 32 + kb;
        const short8 af = *(const short8*)(hall + row_a * H_ + k0);
        #pragma unroll
        for (int i = 0; i < 4; i++) {
            const int n = tile_n + i * 16 + (l & 15);
            const short8 bv = *(const short8*)(Woutb + n * H_ + k0);
            acc[i] = __builtin_amdgcn_mfma_f32_16x16x32_bf16(af, bv, acc[i], 0, 0, 0);
        }
    }

    const int m_base = tile_m + (l >> 4) * 4;
    #pragma unroll
    for (int i = 0; i < 4; i++) {
        const int n = tile_n + i * 16 + (l & 15);
        const float bias = bout[n];
        #pragma unroll
        for (int r = 0; r < 4; r++) {
            const int m = m_base + r;
            const int t = m >> 7;
            const int bb = m & 127;
            out[(size_t)(bb * TDEC + t) * V_ + n] = acc[i][r] + bias;
        }
    }
}

// ---------------------------------------------------------------------------
extern "C" void kernel_launch(void* const* d_in, const int* in_sizes, int n_in,
                              void* d_out, int out_size, void* d_ws, size_t ws_size,
                              hipStream_t stream) {
    const int*   inputs  = (const int*)d_in[0];
    const int*   targets = (const int*)d_in[1];
    const float* emb     = (const float*)d_in[2];
    const float* Wih_f   = (const float*)d_in[3];
    const float* Whh_f   = (const float*)d_in[4];
    const float* bih_f   = (const float*)d_in[5];
    const float* bhh_f   = (const float*)d_in[6];
    const float* Wih_b   = (const float*)d_in[7];
    const float* Whh_b   = (const float*)d_in[8];
    const float* bih_b   = (const float*)d_in[9];
    const float* bhh_b   = (const float*)d_in[10];
    const float* W1      = (const float*)d_in[11];
    const float* b1      = (const float*)d_in[12];
    const float* W2      = (const float*)d_in[13];
    const float* b2      = (const float*)d_in[14];
    const float* Wihd    = (const float*)d_in[15];
    const float* Whhd    = (const float*)d_in[16];
    const float* bihd    = (const float*)d_in[17];
    const float* bhhd    = (const float*)d_in[18];
    const float* Wout    = (const float*)d_in[19];
    const float* bout    = (const float*)d_in[20];
    float* out = (float*)d_out;

    // Staging at the front of d_out (245.76 MB). The logits kernel runs last
    // and overwrites every element of d_out with the real output.
    u16* outputs = (u16*)d_out;                         // bf16 B*S*H = 16,777,216 B
    u16* enc     = (u16*)((char*)d_out + 16777216);     // bf16 B*S*H = 16,777,216 B
    u16* W1b     = (u16*)((char*)d_out + 33554432);     // bf16 H*H   =     32,768 B

    // d_ws: small state only (8.82 MB total) — layout validated in R3.
    char* ws = (char*)d_ws;
    float* sn    = (float*)(ws);                 // B*H  f32    =  65,536 B
    float* t2    = (float*)(ws + 65536);         // B*H  f32    =  65,536 B
    u16*   h_all = (u16*)(ws + 131072);          // 15*B*H bf16 = 491,520 B
    u16*   Woutb = (u16*)(ws + 622592);          // V*H bf16    = 8,192,000 B

    encoder_kernel<<<256, 64, 0, stream>>>(inputs, emb, Wih_f, Whh_f, bih_f, bhh_f,
                                           Wih_b, Whh_b, bih_b, bhh_b, outputs, sn);
    t2_kernel<<<128, 128, 0, stream>>>(sn, W2, b2, t2);
    cvt_bf16_kernel<<<H_ * H_ / 1024, 256, 0, stream>>>(W1, W1b);
    cvt_bf16_kernel<<<V_ * H_ / 1024, 256, 0, stream>>>(Wout, Woutb);
    gate_mfma_kernel<<<B_ * S_ / 64, 256, 0, stream>>>(outputs, W1b, b1, t2, enc);
    decoder_kernel<<<128, 256, 0, stream>>>(targets, emb, Wihd, Whhd, bihd, bhhd,
                                            enc, sn, h_all);
    logits_kernel<<<dim3(500, 30), 256, 0, stream>>>(h_all, Woutb, bout, out);
}